// Round 15
// baseline (140.747 us; speedup 1.0000x reference)
//
#include <hip/hip_runtime.h>

// MultiHeadAttention: B=2, S=2048, H=1024, NH=16, HD=64
// v8: attn moves to 3-buffer counted-vmcnt pipeline (T4: never drain to 0);
// stage t+2 in flight, wait vmcnt(5) per tile. Rest identical to v7.

#define BD 2
#define SD 2048
#define HDIM 1024
#define NHD 16
#define HDD 64
#define NTOK 4096  // BD*SD
#define QSCALE 0.1803368801111204f  // (1/sqrt(64)) * log2(e), folded into Q

typedef float f32x4 __attribute__((ext_vector_type(4)));
typedef _Float16 f16x8 __attribute__((ext_vector_type(8)));
typedef _Float16 f16x4 __attribute__((ext_vector_type(4)));
typedef __fp16 fp16x2 __attribute__((ext_vector_type(2)));

__device__ __forceinline__ f32x4 mfma_f16(f16x8 a, f16x8 b, f32x4 c) {
  return __builtin_amdgcn_mfma_f32_16x16x32_f16(a, b, c, 0, 0, 0);
}

// pack two f32 -> one u32 of 2 f16 (RTZ)
__device__ __forceinline__ unsigned int pk2h(float lo, float hi) {
  fp16x2 v = __builtin_amdgcn_cvt_pkrtz(lo, hi);
  return __builtin_bit_cast(unsigned int, v);
}

// ---------------- convert f32 -> f16 ----------------
__global__ void convert_kernel(const float* __restrict__ x,
                               const float* __restrict__ wq, const float* __restrict__ wk,
                               const float* __restrict__ wv, const float* __restrict__ wo,
                               _Float16* __restrict__ dst) {
  const int total4 = (8 * 1024 * 1024) / 4;
  for (int idx = blockIdx.x * blockDim.x + threadIdx.x; idx < total4;
       idx += gridDim.x * blockDim.x) {
    int e = idx * 4;
    const float* s;
    if (e < 4 * 1024 * 1024) {
      s = x + e;
    } else {
      int w = (e - 4 * 1024 * 1024) >> 20;
      int off = e & 1048575;
      s = (w == 0 ? wq : w == 1 ? wk : w == 2 ? wv : wo) + off;
    }
    float4 v = *(const float4*)s;
    f16x4 h;
    h[0] = (_Float16)v.x; h[1] = (_Float16)v.y;
    h[2] = (_Float16)v.z; h[3] = (_Float16)v.w;
    *(f16x4*)(dst + e) = h;
  }
}

// ---------------- 128x128 GEMM mainloop (C = A * B^T form) ----------------
__device__ __forceinline__ void gemm_mainloop(
    const _Float16* __restrict__ Ap, const _Float16* __restrict__ Bp,
    int i0, int j0, _Float16* As, _Float16* Bs, f32x4 acc[4][4]) {
  const int tid = threadIdx.x;
  const int wid = tid >> 6, lane = tid & 63;
  const int lr = lane & 15, lg = lane >> 4;
  const int wm = wid >> 1, wn = wid & 1;
  const int srow = lane >> 2;
  const int scol = (lane & 3) * 8;

  for (int k0 = 0; k0 < HDIM; k0 += 32) {
#pragma unroll
    for (int it = 0; it < 2; ++it) {
      int rb = (wid * 2 + it) * 16;
      const _Float16* ga = Ap + (size_t)(i0 + rb + srow) * HDIM + k0 + scol;
      const _Float16* gb = Bp + (size_t)(j0 + rb + srow) * HDIM + k0 + scol;
      __builtin_amdgcn_global_load_lds(
          (__attribute__((address_space(1))) void*)ga,
          (__attribute__((address_space(3))) void*)(As + (wid * 2 + it) * 512), 16, 0, 0);
      __builtin_amdgcn_global_load_lds(
          (__attribute__((address_space(1))) void*)gb,
          (__attribute__((address_space(3))) void*)(Bs + (wid * 2 + it) * 512), 16, 0, 0);
    }
    __syncthreads();
    f16x8 af[4], bf[4];
#pragma unroll
    for (int mt = 0; mt < 4; mt++)
      af[mt] = *(const f16x8*)(As + (wm * 64 + mt * 16 + lr) * 32 + lg * 8);
#pragma unroll
    for (int nt = 0; nt < 4; nt++)
      bf[nt] = *(const f16x8*)(Bs + (wn * 64 + nt * 16 + lr) * 32 + lg * 8);
#pragma unroll
    for (int mt = 0; mt < 4; mt++)
#pragma unroll
      for (int nt = 0; nt < 4; nt++)
        acc[mt][nt] = mfma_f16(af[mt], bf[nt], acc[mt][nt]);
    __syncthreads();
  }
}

// ---------------- fused QKV projection ----------------
__global__ __launch_bounds__(256) void gemm_qkv(
    const _Float16* __restrict__ xb,
    const _Float16* __restrict__ wqb, const _Float16* __restrict__ wkb,
    const _Float16* __restrict__ wvb,
    const float* __restrict__ bq, const float* __restrict__ bk,
    const float* __restrict__ bv,
    _Float16* __restrict__ Qo, _Float16* __restrict__ Ko, _Float16* __restrict__ Vt) {
  __shared__ __attribute__((aligned(16))) _Float16 As[128 * 32];
  __shared__ __attribute__((aligned(16))) _Float16 Bs[128 * 32];
  const int bx = blockIdx.x;
  const int mat = bx >> 8;  // 0=Q, 1=K, 2=V
  const int sub = bx & 255;
  const _Float16 *Ap, *Bp;
  int i0, j0;
  if (mat < 2) {
    Ap = xb; Bp = (mat ? wkb : wqb);
    i0 = (sub >> 3) * 128;
    j0 = (sub & 7) * 128;
  } else {
    Ap = wvb; Bp = xb;
    i0 = (sub & 7) * 128;
    j0 = (sub >> 3) * 128;
  }
  f32x4 acc[4][4];
#pragma unroll
  for (int a = 0; a < 4; a++)
#pragma unroll
    for (int b = 0; b < 4; b++) acc[a][b] = (f32x4){0.f, 0.f, 0.f, 0.f};

  gemm_mainloop(Ap, Bp, i0, j0, As, Bs, acc);

  const int tid = threadIdx.x;
  const int wid = tid >> 6, lane = tid & 63;
  const int lr = lane & 15, lg = lane >> 4;
  const int wm = wid >> 1, wn = wid & 1;
  const float* bias = (mat == 0 ? bq : mat == 1 ? bk : bv);

#pragma unroll
  for (int mt = 0; mt < 4; mt++) {
#pragma unroll
    for (int nt = 0; nt < 4; nt++) {
      int i = i0 + wm * 64 + mt * 16 + 4 * lg;
      int j = j0 + wn * 64 + nt * 16 + lr;
      if (mat < 2) {
        float bj = bias[j];
        int h = j >> 6, d = j & 63;
        _Float16* dst = (mat ? Ko : Qo);
        float scl = (mat == 0) ? QSCALE : 1.0f;
#pragma unroll
        for (int r = 0; r < 4; r++) {
          int tok = i + r;
          int b = tok >> 11, s = tok & 2047;
          dst[(((size_t)(b * NHD + h)) * SD + s) * HDD + d] =
              (_Float16)((acc[mt][nt][r] + bj) * scl);
        }
      } else {
        int tok = j;
        int b = tok >> 11, s = tok & 2047;
#pragma unroll
        for (int r = 0; r < 4; r++) {
          int wr = i + r;
          int h = wr >> 6, d = wr & 63;
          Vt[((size_t)(b * NHD + h) * HDD + d) * SD + s] =
              (_Float16)(acc[mt][nt][r] + bias[wr]);
        }
      }
    }
  }
}

// ---------------- output projection: out = attn @ Wo^T + bo (f32) ----------------
__global__ __launch_bounds__(256) void gemm_out(
    const _Float16* __restrict__ attn, const _Float16* __restrict__ wob,
    const float* __restrict__ bo, float* __restrict__ out) {
  __shared__ __attribute__((aligned(16))) _Float16 As[128 * 32];
  __shared__ __attribute__((aligned(16))) _Float16 Bs[128 * 32];
  const int sub = blockIdx.x;
  const int i0 = (sub >> 3) * 128, j0 = (sub & 7) * 128;
  f32x4 acc[4][4];
#pragma unroll
  for (int a = 0; a < 4; a++)
#pragma unroll
    for (int b = 0; b < 4; b++) acc[a][b] = (f32x4){0.f, 0.f, 0.f, 0.f};

  gemm_mainloop(attn, wob, i0, j0, As, Bs, acc);

  const int tid = threadIdx.x;
  const int wid = tid >> 6, lane = tid & 63;
  const int lr = lane & 15, lg = lane >> 4;
  const int wm = wid >> 1, wn = wid & 1;
#pragma unroll
  for (int mt = 0; mt < 4; mt++) {
#pragma unroll
    for (int nt = 0; nt < 4; nt++) {
      int i = i0 + wm * 64 + mt * 16 + 4 * lg;
      int j = j0 + wn * 64 + nt * 16 + lr;
      float bj = bo[j];
#pragma unroll
      for (int r = 0; r < 4; r++)
        out[(size_t)(i + r) * HDIM + j] = acc[mt][nt][r] + bj;
    }
  }
}

// ---------------- flash attention v8 ----------------
// v7 + 3-buffer counted-vmcnt pipeline: stage(t+2) issued each tile, wait
// vmcnt(5) (= exactly the NEXT tile's 5 loads stay in flight; current tile's
// loads proven complete). vmcnt never drains to 0 in the loop; issue->wait
// distance ~2 tiles. Barrier per tile unchanged (protects cross-wave read of
// staged buffers + WAR on the buffer being overwritten, which was last read
// at tile t-1 -> all waves past it once they reach barrier t).
__global__ __launch_bounds__(512) void attn_kernel(
    const _Float16* __restrict__ Q, const _Float16* __restrict__ K,
    const _Float16* __restrict__ VT, _Float16* __restrict__ AO) {
  const int g = blockIdx.x;
  const int xcd = g & 7, idx = g >> 3;
  const int qb = idx & 15;
  const int bh = xcd * 4 + (idx >> 4);
  const int tid = threadIdx.x, wv = tid >> 6, lane = tid & 63;
  const int lr = lane & 15, lg = lane >> 4;
  const int q0 = qb * 128 + wv * 16;
  const _Float16* Qh = Q + (size_t)bh * SD * HDD;
  const _Float16* Kh = K + (size_t)bh * SD * HDD;
  const _Float16* Vh = VT + (size_t)bh * HDD * SD;

  __shared__ __attribute__((aligned(16))) _Float16 Ks[3][2][64][32];  // [buf][kf][key][d-half]
  __shared__ __attribute__((aligned(16))) _Float16 Vs[3][2][64][32];  // [buf][kf][d][pos]

  // K staging: wave wv stages kf=wv&1, key-rows (wv>>1)*16..+15 (one 16B instr)
  const int krow = lane >> 2;
  const int kswz = (((lane & 3) ^ ((lane >> 3) & 3)) * 8);
  const int kkf = wv & 1, krb = (wv >> 1) * 16;

  // V staging: wave wv stages d-rows wv*8..wv*8+7 per kf (two 4B instrs each)
  const int m  = lane & 15;
  const int u  = m & 3;
  const int sg = m >> 2;
  const int r4 = lane >> 4;
  const int c2 = (r4 >> 1) & 1;
  const int keyoff_e = 16 * (u >> 1) + 4 * (sg ^ c2)       + 2 * (u & 1);
  const int keyoff_o = 16 * (u >> 1) + 4 * (sg ^ (c2 | 2)) + 2 * (u & 1);
  const _Float16* Vrow[2];
  Vrow[0] = Vh + (size_t)(wv * 8 + 0 + r4) * SD + keyoff_e;
  Vrow[1] = Vh + (size_t)(wv * 8 + 4 + r4) * SD + keyoff_o;

  auto stage = [&](int b, int kv0) {  // 5 global_load_lds per wave
    const _Float16* gk = Kh + (size_t)(kv0 + krb + krow) * HDD + kkf * 32 + kswz;
    __builtin_amdgcn_global_load_lds(
        (__attribute__((address_space(1))) void*)gk,
        (__attribute__((address_space(3))) void*)(&Ks[b][kkf][krb][0]), 16, 0, 0);
#pragma unroll
    for (int kf = 0; kf < 2; kf++)
#pragma unroll
      for (int i = 0; i < 2; i++) {
        const _Float16* gv = Vrow[i] + kv0 + kf * 32;
        __builtin_amdgcn_global_load_lds(
            (__attribute__((address_space(1))) void*)gv,
            (__attribute__((address_space(3))) void*)(&Vs[b][kf][wv * 8 + i * 4][0]), 4, 0, 0);
      }
  };

  const int fswz = (lg ^ ((lr >> 1) & 3)) * 8;

  // Q fragments (pre-scaled by QSCALE): B-operand, lane lr = q-row q0+lr
  f16x8 qf[2];
#pragma unroll
  for (int kf = 0; kf < 2; kf++)
    qf[kf] = *(const f16x8*)(Qh + (size_t)(q0 + lr) * HDD + kf * 32 + lg * 8);

  f32x4 acc[4];
#pragma unroll
  for (int i = 0; i < 4; i++) acc[i] = (f32x4){0.f, 0.f, 0.f, 0.f};
  float mrun = -1e30f;
  float ls0 = 0.f, ls1 = 0.f, ls2 = 0.f, ls3 = 0.f;

  stage(0, 0);       // tile 0 -> buf 0
  stage(1, 64);      // tile 1 -> buf 1
  int cur = 0;

  for (int t = 0; t < SD / 64; ++t) {
    // stage(t) complete; stage(t+1)'s 5 loads (+nothing else) may remain in flight
    asm volatile("s_waitcnt vmcnt(5)" ::: "memory");
    __builtin_amdgcn_s_barrier();
    int nb = cur + 2; if (nb >= 3) nb -= 3;              // buffer of t-1, free now
    stage(nb, ((t + 2) & (SD / 64 - 1)) * 64);           // issue t+2 (wrap: dummy)

    // ---- S^T = K Q^T: lane = (q=lr), keys 16nt+4lg+r (log2 units) ----
    f32x4 sc[4];
#pragma unroll
    for (int nt = 0; nt < 4; nt++) sc[nt] = (f32x4){0.f, 0.f, 0.f, 0.f};
    __builtin_amdgcn_s_setprio(1);
#pragma unroll
    for (int nt = 0; nt < 4; nt++)
#pragma unroll
      for (int kf = 0; kf < 2; kf++) {
        f16x8 kfr = *(const f16x8*)&Ks[cur][kf][nt * 16 + lr][fswz];
        sc[nt] = mfma_f16(kfr, qf[kf], sc[nt]);  // swapped operands
      }
    __builtin_amdgcn_s_setprio(0);

    // ---- max via max3 tree (depth ~4) ----
    float t0 = fmaxf(fmaxf(sc[0][0], sc[0][1]), sc[0][2]);
    float t1 = fmaxf(fmaxf(sc[0][3], sc[1][0]), sc[1][1]);
    float t2 = fmaxf(fmaxf(sc[1][2], sc[1][3]), sc[2][0]);
    float t3 = fmaxf(fmaxf(sc[2][1], sc[2][2]), sc[2][3]);
    float t4 = fmaxf(fmaxf(sc[3][0], sc[3][1]), sc[3][2]);
    float tm = fmaxf(fmaxf(fmaxf(t0, t1), fmaxf(t2, t3)), fmaxf(t4, sc[3][3]));
    tm = fmaxf(tm, __shfl_xor(tm, 16));
    tm = fmaxf(tm, __shfl_xor(tm, 32));

    if (__any(tm - mrun > 8.0f)) {  // defer-max (THR=8)
      float mn = fmaxf(mrun, tm);
      float fm = exp2f(mrun - mn);
      mrun = mn;
      ls0 *= fm; ls1 *= fm; ls2 *= fm; ls3 *= fm;
#pragma unroll
      for (int ntd = 0; ntd < 4; ntd++)
#pragma unroll
        for (int r = 0; r < 4; r++) acc[ntd][r] *= fm;
    }

    // ---- kf-half 0: exp2 keys 0..31, pack, PV ----
    {
      float p0[4], p1[4];
#pragma unroll
      for (int r = 0; r < 4; r++) p0[r] = exp2f(sc[0][r] - mrun);
#pragma unroll
      for (int r = 0; r < 4; r++) p1[r] = exp2f(sc[1][r] - mrun);
      ls0 += (p0[0] + p0[1]) + (p0[2] + p0[3]);
      ls1 += (p1[0] + p1[1]) + (p1[2] + p1[3]);
      unsigned int pw[4];
      pw[0] = pk2h(p0[0], p0[1]); pw[1] = pk2h(p0[2], p0[3]);
      pw[2] = pk2h(p1[0], p1[1]); pw[3] = pk2h(p1[2], p1[3]);
      f16x8 pb = __builtin_bit_cast(f16x8, *(unsigned int(*)[4])pw);
      __builtin_amdgcn_s_setprio(1);
#pragma unroll
      for (int ntd = 0; ntd < 4; ntd++) {
        f16x8 vf = *(const f16x8*)&Vs[cur][0][ntd * 16 + lr][fswz];
        acc[ntd] = mfma_f16(vf, pb, acc[ntd]);
      }
      __builtin_amdgcn_s_setprio(0);
    }
    // ---- kf-half 1: exp2 keys 32..63, pack, PV ----
    {
      float p0[4], p1[4];
#pragma unroll
      for (int r = 0; r < 4; r++) p0[r] = exp2f(sc[2][r] - mrun);
#pragma unroll
      for (int r = 0; r < 4; r++) p1[r] = exp2f(sc[3][r] - mrun);
      ls2 += (p0[0] + p0[1]) + (p0[2] + p0[3]);
      ls3 += (p1[0] + p1[1]) + (p1[2] + p1[3]);
      unsigned int pw[4];
      pw[0] = pk2h(p0[0], p0[1]); pw[1] = pk2h(p0[2], p0[3]);
      pw[2] = pk2h(p1[0], p1[1]); pw[3] = pk2h(p1[2], p1[3]);
      f16x8 pb = __builtin_bit_cast(f16x8, *(unsigned int(*)[4])pw);
      __builtin_amdgcn_s_setprio(1);
#pragma unroll
      for (int ntd = 0; ntd < 4; ntd++) {
        f16x8 vf = *(const f16x8*)&Vs[cur][1][ntd * 16 + lr][fswz];
        acc[ntd] = mfma_f16(vf, pb, acc[ntd]);
      }
      __builtin_amdgcn_s_setprio(0);
    }
    cur = (cur + 1 == 3) ? 0 : cur + 1;
  }

  // ---- epilogue: merge partials, cross-lane reduce, normalize, write ----
  float lsum = (ls0 + ls1) + (ls2 + ls3);
  lsum += __shfl_xor(lsum, 16);
  lsum += __shfl_xor(lsum, 32);
  float inv = 1.0f / lsum;

  const int b = bh >> 4, h = bh & 15;
  _Float16* aoRow = AO + (size_t)(b * SD + q0 + lr) * HDIM + h * 64;
#pragma unroll
  for (int ntd = 0; ntd < 4; ntd++) {
    f16x4 o;
#pragma unroll
    for (int r = 0; r < 4; r++) o[r] = (_Float16)(acc[ntd][r] * inv);
    *(f16x4*)(aoRow + ntd * 16 + 4 * lg) = o;
  }
}

extern "C" void kernel_launch(void* const* d_in, const int* in_sizes, int n_in,
                              void* d_out, int out_size, void* d_ws, size_t ws_size,
                              hipStream_t stream) {
  const float* x  = (const float*)d_in[0];
  const float* Wq = (const float*)d_in[1];
  const float* bq = (const float*)d_in[2];
  const float* Wk = (const float*)d_in[3];
  const float* bk = (const float*)d_in[4];
  const float* Wv = (const float*)d_in[5];
  const float* bv = (const float*)d_in[6];
  const float* Wo = (const float*)d_in[7];
  const float* bo = (const float*)d_in[8];
  float* out = (float*)d_out;

  _Float16* xb  = (_Float16*)d_ws;            // 4M
  _Float16* wqb = xb + 4 * 1024 * 1024;       // 1M
  _Float16* wkb = wqb + 1024 * 1024;
  _Float16* wvb = wkb + 1024 * 1024;
  _Float16* wob = wvb + 1024 * 1024;
  _Float16* Qb  = wob + 1024 * 1024;          // 4M  [bh][s][d]  (pre-scaled)
  _Float16* Kb  = Qb + 4 * 1024 * 1024;       // 4M  [bh][s][d]
  _Float16* Vt  = Kb + 4 * 1024 * 1024;       // 4M  [bh][d][s]
  _Float16* AOb = Vt + 4 * 1024 * 1024;       // 4M  [token][H]

  convert_kernel<<<dim3(1024), dim3(256), 0, stream>>>(x, Wq, Wk, Wv, Wo, xb);
  gemm_qkv<<<dim3(768), dim3(256), 0, stream>>>(xb, wqb, wkb, wvb, bq, bk, bv, Qb, Kb, Vt);
  attn_kernel<<<dim3(512), dim3(512), 0, stream>>>(Qb, Kb, Vt, AOb);
  gemm_out<<<dim3(256), dim3(256), 0, stream>>>(AOb, wob, bo, out);
}